// Round 20
// baseline (101.638 us; speedup 1.0000x reference)
//
#include <hip/hip_runtime.h>
#include <cstdint>
#include <cstddef>

#define BQ   4
#define CQ   64
#define GH   128
#define GW   512
#define SWW  512
#define HALF 256
#define HWQ  (GH * GW)        // 65536
#define NPIX (BQ * HWQ)       // 262144
#define NSEG (BQ * SWW * SWW) // 1048576

typedef unsigned long long u64;
typedef float f32x4 __attribute__((ext_vector_type(4)));

// Monotone order-preserving f32 -> u32 map: encoded compare == float compare.
__device__ __forceinline__ unsigned ord_encode(float f) {
    unsigned b = __float_as_uint(f);
    return (b & 0x80000000u) ? ~b : (b | 0x80000000u);
}

// GOLDEN (r13): fused project+segmin+winner, ONE packed u64 atomicMin per
// kept pixel: key = (ord_encode(y) << 32) | ~pixel_id  (min y, tie->last id).
// f32 chain with reciprocal-multiply binning. DO NOT TOUCH.
__global__ void k_project(const float* __restrict__ ck,
                          const float* __restrict__ depth,
                          const float* __restrict__ mppp,
                          u64* __restrict__ seg) {
#pragma clang fp contract(off)
    int i = blockIdx.x * blockDim.x + threadIdx.x; // exactly NPIX threads
    int b   = i >> 16;       // / HWQ
    int rem = i & (HWQ - 1);
    int v   = rem >> 9;      // / GW
    int u   = rem & (GW - 1);

    const float* K = ck + b * 9;
    float K00 = K[0] * 0.5f;           // exact (250)
    float K02 = K[2] * 0.5f;           // exact (256)
    float K11 = K[4] * 0.5f;           // exact (250)
    float K12 = K[5] * 0.5f;           // exact (64)
    float Ki00 = 1.0f / K00;
    float Ki02 = (-K02) / K00;
    float Ki11 = 1.0f / K11;
    float Ki12 = (-K12) / K11;

    float d   = depth[i];
    float mpp = mppp[0];

    float tx = Ki00 * (float)u;
    asm volatile("" : "+v"(tx));
    float xw = tx + Ki02;
    float ty = Ki11 * (float)v;
    asm volatile("" : "+v"(ty));
    float yw = ty + Ki12;

    float x3 = (xw * d) * 1.2f;
    float y3 = (yw * d) * 1.2f;
    float z3 = d * 1.2f;

    float r = 1.0f / mpp;              // rn32(1/0.2f) == 5.0f exactly
    asm volatile("" : "+v"(r));
    float x = truncf(x3 * r);
    float z = truncf(z3 * r);

    bool kept = (x >= -(float)HALF) && (x <= (float)(HALF - 1)) &&
                (z >= -(float)HALF) && (z <= (float)(HALF - 1));

    if (kept) {
        int cell = b * (SWW * SWW) + ((int)x + HALF) * SWW + ((int)z + HALF);
        u64 key = ((u64)ord_encode(y3) << 32) | (u64)(~(unsigned)i);
        atomicMin(seg + cell, key);
    }
}

// img [b][c][p] -> T [b][p][c]: LDS tile transpose, 64c x 64p tiles.
// img read nontemporal (read-once; keep L2 for T), T stores normal (reused).
__global__ void __launch_bounds__(256) k_transpose(const float* __restrict__ img,
                                                   float* __restrict__ T) {
    __shared__ float lds[64][65];
    int b  = blockIdx.y;
    int p0 = blockIdx.x * 64;
    int t  = threadIdx.x;

    const f32x4* img4 = (const f32x4*)img;
    #pragma unroll
    for (int iter = 0; iter < 4; ++iter) {
        int idx = iter * 256 + t;          // 64c x 16p4
        int c   = idx >> 4;
        int p4  = idx & 15;
        f32x4 v = __builtin_nontemporal_load(
            &img4[((size_t)(b * CQ + c) * HWQ + p0) / 4 + p4]);
        lds[c][p4 * 4 + 0] = v.x;
        lds[c][p4 * 4 + 1] = v.y;
        lds[c][p4 * 4 + 2] = v.z;
        lds[c][p4 * 4 + 3] = v.w;
    }
    __syncthreads();
    f32x4* T4 = (f32x4*)T;
    #pragma unroll
    for (int iter = 0; iter < 4; ++iter) {
        int idx = iter * 256 + t;          // 64p x 16c4
        int p   = idx >> 4;
        int c4  = idx & 15;
        f32x4 v;
        v.x = lds[c4 * 4 + 0][p];
        v.y = lds[c4 * 4 + 1][p];
        v.z = lds[c4 * 4 + 2][p];
        v.w = lds[c4 * 4 + 3][p];
        T4[(size_t)(b * HWQ + p0 + p) * 16 + c4] = v;
    }
}

// R18 emit (r17 intent): phase0 stages 128 decoded pid-bases in LDS (was:
// 16x redundant u64 seg loads per cell). Gather reads pbase[cl] (16 lanes
// same idx -> LDS broadcast, free). LDS stride 69: gather-write banks
// (5cl+4c4)%32 2-way free; read banks (5zi+c)%32 full spread. Output
// stores nontemporal.
__global__ void __launch_bounds__(512) k_emit2(const u64* __restrict__ seg,
                                               const float* __restrict__ T,
                                               float* __restrict__ out) {
    __shared__ float lds[128 * 69];
    __shared__ int pbase[128];
    int bid   = blockIdx.x;          // BQ*SWW*4
    int chunk = bid & 3;
    int row   = bid >> 2;
    int b     = row >> 9;
    int xi    = row & (SWW - 1);
    int zi0   = chunk * 128;
    int t     = threadIdx.x;

    if (t < 128) {
        u64 s = seg[((size_t)row << 9) + zi0 + t];
        pbase[t] = (s != ~0ULL) ? (int)((~(unsigned)(s & 0xFFFFFFFFu)) & (HWQ - 1)) : -1;
    }
    __syncthreads();

    const f32x4* T4 = (const f32x4*)T;
    size_t tb = (size_t)b * HWQ * 16;
    // gather: 128 cells x 16 float4 = 2048, 4 iters
    #pragma unroll
    for (int iter = 0; iter < 4; ++iter) {
        int idx = iter * 512 + t;
        int cl  = idx >> 4;          // cell_local 0..127
        int c4  = idx & 15;
        int p   = pbase[cl];
        f32x4 v = (f32x4)(0.f);
        if (p >= 0) v = T4[tb + (size_t)p * 16 + c4];
        float* dst = &lds[cl * 69 + c4 * 4];
        dst[0] = v.x; dst[1] = v.y; dst[2] = v.z; dst[3] = v.w;
    }
    __syncthreads();
    // write: 64 c x 128 zi, coalesced over zi, nontemporal
    float* orow = out + ((size_t)(b * CQ) * SWW + xi) * SWW;
    #pragma unroll
    for (int iter = 0; iter < 16; ++iter) {
        int zi = t & 127;
        int c  = iter * 4 + (t >> 7);
        __builtin_nontemporal_store(lds[zi * 69 + c],
                                    &orow[(size_t)c * (SWW * SWW) + zi0 + zi]);
    }
}

// Fallback emit (no T) if ws too small.
__global__ void __launch_bounds__(512) k_emit(const u64* __restrict__ seg,
                                              const float* __restrict__ img,
                                              float* __restrict__ out) {
    int bid = blockIdx.x;
    int b   = bid >> 9;
    int xi  = bid & (SWW - 1);
    int zi  = threadIdx.x;

    u64 s = seg[((size_t)(b * SWW + xi) << 9) + zi];
    int src = -1;
    if (s != ~0ULL) {
        int pid = (int)(~(unsigned)(s & 0xFFFFFFFFu));
        src = b * (CQ * HWQ) + (pid & (HWQ - 1));
    }

    float* op = out + ((size_t)(b * CQ) * SWW + xi) * SWW + zi;
    #pragma unroll 4
    for (int c = 0; c < CQ; ++c) {
        float val = (src >= 0) ? img[src + c * HWQ] : 0.0f;
        __builtin_nontemporal_store(val, &op[(size_t)c * SWW * SWW]);
    }
}

extern "C" void kernel_launch(void* const* d_in, const int* in_sizes, int n_in,
                              void* d_out, int out_size, void* d_ws, size_t ws_size,
                              hipStream_t stream) {
    const float* img   = (const float*)d_in[0];
    const float* ck    = (const float*)d_in[1];
    const float* depth = (const float*)d_in[2];
    const float* mpp   = (const float*)d_in[3];
    float* out = (float*)d_out;

    char* ws = (char*)d_ws;
    u64*   seg  = (u64*)(ws + 256);                     // NSEG*8 = 8 MB
    size_t offT = 256 + (size_t)NSEG * 8;               // 16B-aligned
    float* T    = (float*)(ws + offT);                  // 67 MB
    size_t need = offT + (size_t)NPIX * CQ * 4;

    // seg init: all bytes 0xFF == ~0ULL == (+inf key, empty)
    (void)hipMemsetAsync(seg, 0xFF, (size_t)NSEG * 8, stream);
    k_project<<<NPIX / 256, 256, 0, stream>>>(ck, depth, mpp, seg);
    if (ws_size >= need) {
        k_transpose<<<dim3(HWQ / 64, BQ), 256, 0, stream>>>(img, T);
        k_emit2    <<<BQ * SWW * 4, 512, 0, stream>>>(seg, T, out);
    } else {
        k_emit     <<<BQ * SWW, 512, 0, stream>>>(seg, img, out);
    }
}

// Round 21
// 94.044 us; speedup vs baseline: 1.0808x; 1.0808x over previous
//
#include <hip/hip_runtime.h>
#include <cstdint>
#include <cstddef>

#define BQ   4
#define CQ   64
#define GH   128
#define GW   512
#define SWW  512
#define HALF 256
#define HWQ  (GH * GW)        // 65536
#define NPIX (BQ * HWQ)       // 262144
#define NSEG (BQ * SWW * SWW) // 1048576

typedef unsigned long long u64;

// Monotone order-preserving f32 -> u32 map: encoded compare == float compare.
__device__ __forceinline__ unsigned ord_encode(float f) {
    unsigned b = __float_as_uint(f);
    return (b & 0x80000000u) ? ~b : (b | 0x80000000u);
}

// R21: fused prep kernel. Blocks [0,4096): img [b][c][p] -> T [b][p][c]
// LDS tile transpose (r16-proven body). Blocks [4096,5120): GOLDEN r13
// projection chain (f32, reciprocal-multiply binning, packed u64 atomicMin:
// key = (ord_encode(y) << 32) | ~pixel_id -> min y, tie -> last id).
// Independent writes (T vs seg) -> safe to co-schedule; project hides under
// transpose's memory traffic. FP chain DO NOT TOUCH.
__global__ void __launch_bounds__(256) k_prep(const float* __restrict__ img,
                                              float* __restrict__ T,
                                              const float* __restrict__ ck,
                                              const float* __restrict__ depth,
                                              const float* __restrict__ mppp,
                                              u64* __restrict__ seg) {
#pragma clang fp contract(off)
    __shared__ float lds[64][65];
    int bid = blockIdx.x;
    int t   = threadIdx.x;

    if (bid < 4096) {
        // ---------------- transpose ----------------
        int b  = bid >> 10;
        int p0 = (bid & 1023) * 64;

        const float4* img4 = (const float4*)img;
        #pragma unroll
        for (int iter = 0; iter < 4; ++iter) {
            int idx = iter * 256 + t;          // 64c x 16p4
            int c   = idx >> 4;
            int p4  = idx & 15;
            float4 v = img4[((size_t)(b * CQ + c) * HWQ + p0) / 4 + p4];
            lds[c][p4 * 4 + 0] = v.x;
            lds[c][p4 * 4 + 1] = v.y;
            lds[c][p4 * 4 + 2] = v.z;
            lds[c][p4 * 4 + 3] = v.w;
        }
        __syncthreads();
        float4* T4 = (float4*)T;
        #pragma unroll
        for (int iter = 0; iter < 4; ++iter) {
            int idx = iter * 256 + t;          // 64p x 16c4
            int p   = idx >> 4;
            int c4  = idx & 15;
            float4 v;
            v.x = lds[c4 * 4 + 0][p];
            v.y = lds[c4 * 4 + 1][p];
            v.z = lds[c4 * 4 + 2][p];
            v.w = lds[c4 * 4 + 3][p];
            T4[(size_t)(b * HWQ + p0 + p) * 16 + c4] = v;
        }
    } else {
        // ---------------- projection (GOLDEN) ----------------
        int i = (bid - 4096) * 256 + t;        // exactly NPIX threads
        int b   = i >> 16;       // / HWQ
        int rem = i & (HWQ - 1);
        int v   = rem >> 9;      // / GW
        int u   = rem & (GW - 1);

        const float* K = ck + b * 9;
        float K00 = K[0] * 0.5f;           // exact (250)
        float K02 = K[2] * 0.5f;           // exact (256)
        float K11 = K[4] * 0.5f;           // exact (250)
        float K12 = K[5] * 0.5f;           // exact (64)
        float Ki00 = 1.0f / K00;
        float Ki02 = (-K02) / K00;
        float Ki11 = 1.0f / K11;
        float Ki12 = (-K12) / K11;

        float d   = depth[i];
        float mpp = mppp[0];

        float tx = Ki00 * (float)u;
        asm volatile("" : "+v"(tx));
        float xw = tx + Ki02;
        float ty = Ki11 * (float)v;
        asm volatile("" : "+v"(ty));
        float yw = ty + Ki12;

        float x3 = (xw * d) * 1.2f;
        float y3 = (yw * d) * 1.2f;
        float z3 = d * 1.2f;

        float r = 1.0f / mpp;              // rn32(1/0.2f) == 5.0f exactly
        asm volatile("" : "+v"(r));
        float x = truncf(x3 * r);
        float z = truncf(z3 * r);

        bool kept = (x >= -(float)HALF) && (x <= (float)(HALF - 1)) &&
                    (z >= -(float)HALF) && (z <= (float)(HALF - 1));

        if (kept) {
            int cell = b * (SWW * SWW) + ((int)x + HALF) * SWW + ((int)z + HALF);
            u64 key = ((u64)ord_encode(y3) << 32) | (u64)(~(unsigned)i);
            atomicMin(seg + cell, key);
        }
    }
}

// R16-proven emit (reverted from r18's pbase regression): 8192 independent
// blocks, one 128-cell chunk each. Per-lane direct seg load (16 lanes same
// addr -> coalesced broadcast, free). LDS stride 69: gather-write banks
// 2-way (free), read banks full spread. Output stores nontemporal.
__global__ void __launch_bounds__(512) k_emit2(const u64* __restrict__ seg,
                                               const float* __restrict__ T,
                                               float* __restrict__ out) {
    __shared__ float lds[128 * 69];
    int bid   = blockIdx.x;          // BQ*SWW*4
    int chunk = bid & 3;
    int row   = bid >> 2;
    int b     = row >> 9;
    int xi    = row & (SWW - 1);
    int zi0   = chunk * 128;
    int t     = threadIdx.x;

    const float4* T4 = (const float4*)T;
    const u64* srow = seg + ((size_t)row << 9);
    float* orow = out + ((size_t)(b * CQ) * SWW + xi) * SWW;

    // gather: 128 cells x 16 float4 = 2048, 4 iters
    #pragma unroll
    for (int iter = 0; iter < 4; ++iter) {
        int idx = iter * 512 + t;
        int cl  = idx >> 4;          // cell_local 0..127
        int c4  = idx & 15;
        u64 s   = srow[zi0 + cl];
        float4 v = make_float4(0.f, 0.f, 0.f, 0.f);
        if (s != ~0ULL) {
            int pid = (int)(~(unsigned)(s & 0xFFFFFFFFu));
            v = T4[(size_t)(b * HWQ + (pid & (HWQ - 1))) * 16 + c4];
        }
        float* dst = &lds[cl * 69 + c4 * 4];
        dst[0] = v.x; dst[1] = v.y; dst[2] = v.z; dst[3] = v.w;
    }
    __syncthreads();
    // write: 64 c x 128 zi, coalesced over zi, nontemporal
    #pragma unroll
    for (int iter = 0; iter < 16; ++iter) {
        int zi = t & 127;
        int c  = iter * 4 + (t >> 7);
        __builtin_nontemporal_store(lds[zi * 69 + c],
                                    &orow[(size_t)c * (SWW * SWW) + zi0 + zi]);
    }
}

// Fallback emit (no T) if ws too small.
__global__ void __launch_bounds__(512) k_emit(const u64* __restrict__ seg,
                                              const float* __restrict__ img,
                                              float* __restrict__ out) {
    int bid = blockIdx.x;
    int b   = bid >> 9;
    int xi  = bid & (SWW - 1);
    int zi  = threadIdx.x;

    u64 s = seg[((size_t)(b * SWW + xi) << 9) + zi];
    int src = -1;
    if (s != ~0ULL) {
        int pid = (int)(~(unsigned)(s & 0xFFFFFFFFu));
        src = b * (CQ * HWQ) + (pid & (HWQ - 1));
    }

    float* op = out + ((size_t)(b * CQ) * SWW + xi) * SWW + zi;
    #pragma unroll 4
    for (int c = 0; c < CQ; ++c) {
        float val = (src >= 0) ? img[src + c * HWQ] : 0.0f;
        __builtin_nontemporal_store(val, &op[(size_t)c * SWW * SWW]);
    }
}

// Fallback project (standalone) for the no-T path.
__global__ void k_project(const float* __restrict__ ck,
                          const float* __restrict__ depth,
                          const float* __restrict__ mppp,
                          u64* __restrict__ seg) {
#pragma clang fp contract(off)
    int i = blockIdx.x * blockDim.x + threadIdx.x;
    int b   = i >> 16;
    int rem = i & (HWQ - 1);
    int v   = rem >> 9;
    int u   = rem & (GW - 1);

    const float* K = ck + b * 9;
    float K00 = K[0] * 0.5f;
    float K02 = K[2] * 0.5f;
    float K11 = K[4] * 0.5f;
    float K12 = K[5] * 0.5f;
    float Ki00 = 1.0f / K00;
    float Ki02 = (-K02) / K00;
    float Ki11 = 1.0f / K11;
    float Ki12 = (-K12) / K11;

    float d   = depth[i];
    float mpp = mppp[0];

    float tx = Ki00 * (float)u;
    asm volatile("" : "+v"(tx));
    float xw = tx + Ki02;
    float ty = Ki11 * (float)v;
    asm volatile("" : "+v"(ty));
    float yw = ty + Ki12;

    float x3 = (xw * d) * 1.2f;
    float y3 = (yw * d) * 1.2f;
    float z3 = d * 1.2f;

    float r = 1.0f / mpp;
    asm volatile("" : "+v"(r));
    float x = truncf(x3 * r);
    float z = truncf(z3 * r);

    bool kept = (x >= -(float)HALF) && (x <= (float)(HALF - 1)) &&
                (z >= -(float)HALF) && (z <= (float)(HALF - 1));

    if (kept) {
        int cell = b * (SWW * SWW) + ((int)x + HALF) * SWW + ((int)z + HALF);
        u64 key = ((u64)ord_encode(y3) << 32) | (u64)(~(unsigned)i);
        atomicMin(seg + cell, key);
    }
}

extern "C" void kernel_launch(void* const* d_in, const int* in_sizes, int n_in,
                              void* d_out, int out_size, void* d_ws, size_t ws_size,
                              hipStream_t stream) {
    const float* img   = (const float*)d_in[0];
    const float* ck    = (const float*)d_in[1];
    const float* depth = (const float*)d_in[2];
    const float* mpp   = (const float*)d_in[3];
    float* out = (float*)d_out;

    char* ws = (char*)d_ws;
    u64*   seg  = (u64*)(ws + 256);                     // NSEG*8 = 8 MB
    size_t offT = 256 + (size_t)NSEG * 8;               // 16B-aligned
    float* T    = (float*)(ws + offT);                  // 67 MB
    size_t need = offT + (size_t)NPIX * CQ * 4;

    // seg init: all bytes 0xFF == ~0ULL == (+inf key, empty)
    (void)hipMemsetAsync(seg, 0xFF, (size_t)NSEG * 8, stream);
    if (ws_size >= need) {
        k_prep <<<4096 + NPIX / 256, 256, 0, stream>>>(img, T, ck, depth, mpp, seg);
        k_emit2<<<BQ * SWW * 4, 512, 0, stream>>>(seg, T, out);
    } else {
        k_project<<<NPIX / 256, 256, 0, stream>>>(ck, depth, mpp, seg);
        k_emit   <<<BQ * SWW, 512, 0, stream>>>(seg, img, out);
    }
}